// Round 15
// baseline (520.557 us; speedup 1.0000x reference)
//
#include <hip/hip_runtime.h>
#include <stdint.h>

// scores[b,s] = v . tanh( W1@hidden[-1,b] + W2@enc[s,b] + bias ); out = softmax_s
// GEMM: [M=65536,K=1024] x [N=1024,K=1024]^T in bf16 MFMA.
// r15: r14 geometry (256x128 tile, 4 waves 2Mx2N, per-wave 128x64,
// acc[8][4]=128 regs -> ~212 VGPR no-spill) but BK=32: dbuf LDS drops
// 98KB -> 50KB -> 2 blocks/CU (8 waves/CU), fixing r14's 1-wave/SIMD
// starvation. Resource model from r10-r14: ~212 VGPR => 2 waves/SIMD max;
// LDS must be <=75KB to seat both blocks. Counted-vmcnt dbuf (r9-validated):
// vmcnt(6) steady state, drain-0 only on the last K-tile.

#define S_LEN 2048
#define B_SZ 32
#define H_SZ 1024
#define M_TOT (S_LEN * B_SZ)   // 65536
#define K_TOT H_SZ             // 1024
#define NCB 8                  // col-blocks = N / 128
#define BK 32
#define NKB 32                 // K / BK
#define TSA 8192               // A tile shorts: 256 rows * 32 k
#define TSB 4096               // B tile shorts: 128 rows * 32 k

typedef __attribute__((ext_vector_type(8))) short short8;
typedef __attribute__((ext_vector_type(4))) float f32x4;

static __device__ __forceinline__ unsigned short f2bf(float x) {
  uint32_t u = __builtin_bit_cast(uint32_t, x);
  u += 0x7FFFu + ((u >> 16) & 1u);
  return (unsigned short)(u >> 16);
}
static __device__ __forceinline__ uint32_t pack2(float a, float b) {
  return (uint32_t)f2bf(a) | ((uint32_t)f2bf(b) << 16);
}
static __device__ __forceinline__ float fast_tanh(float x) {
  float e = __expf(2.0f * x);
  return 1.0f - 2.0f / (e + 1.0f);
}

// ---------- u[b][h] = dot(attn_w[h, 0:H], hidden[-1,b,:]) + attn_b[h]
__global__ void __launch_bounds__(256) prep_u_kernel(
    const float* __restrict__ hidden, const float* __restrict__ attn_w,
    const float* __restrict__ attn_b, float* __restrict__ u) {
  __shared__ float hs[4][H_SZ];
  const int hc = blockIdx.x;   // 0..3  (h chunk)
  const int bg = blockIdx.y;   // 0..7  (batch group of 4)
  const int tid = threadIdx.x;
  for (int i = tid; i < 4 * H_SZ; i += 256) {
    const int bi = i >> 10, k = i & 1023;
    hs[bi][k] = hidden[(size_t)B_SZ * H_SZ + (size_t)(bg * 4 + bi) * H_SZ + k];
  }
  __syncthreads();
  const int h = hc * 256 + tid;
  const float* wrow = attn_w + (size_t)h * (2 * H_SZ);
  float s0 = 0.f, s1 = 0.f, s2 = 0.f, s3 = 0.f;
#pragma unroll 4
  for (int k = 0; k < H_SZ; k += 4) {
    float4 w4 = *reinterpret_cast<const float4*>(wrow + k);
    s0 += w4.x * hs[0][k] + w4.y * hs[0][k + 1] + w4.z * hs[0][k + 2] + w4.w * hs[0][k + 3];
    s1 += w4.x * hs[1][k] + w4.y * hs[1][k + 1] + w4.z * hs[1][k + 2] + w4.w * hs[1][k + 3];
    s2 += w4.x * hs[2][k] + w4.y * hs[2][k + 1] + w4.z * hs[2][k + 2] + w4.w * hs[2][k + 3];
    s3 += w4.x * hs[3][k] + w4.y * hs[3][k + 1] + w4.z * hs[3][k + 2] + w4.w * hs[3][k + 3];
  }
  const float bb = attn_b[h];
  u[(size_t)(bg * 4 + 0) * H_SZ + h] = s0 + bb;
  u[(size_t)(bg * 4 + 1) * H_SZ + h] = s1 + bb;
  u[(size_t)(bg * 4 + 2) * H_SZ + h] = s2 + bb;
  u[(size_t)(bg * 4 + 3) * H_SZ + h] = s3 + bb;
}

// ---------- enc f32 -> bf16 image tiles [256 rows][32 k];
// 16B slot s4 (0..3) of row r stored at slot (s4 ^ (r&3)).
__global__ void __launch_bounds__(256) prep_a_kernel(
    const float* __restrict__ enc, unsigned short* __restrict__ Aimg) {
  const int idx = blockIdx.x * 256 + threadIdx.x;   // [0, M_TOT*128)
  const int m = idx >> 7, sl = idx & 127;
  const int kb = sl >> 2, s4 = sl & 3;
  const float4* src =
      reinterpret_cast<const float4*>(enc + (size_t)m * K_TOT + kb * BK + s4 * 8);
  float4 f0 = src[0], f1 = src[1];
  uint4 o;
  o.x = pack2(f0.x, f0.y); o.y = pack2(f0.z, f0.w);
  o.z = pack2(f1.x, f1.y); o.w = pack2(f1.z, f1.w);
  const int row = m & 255;
  const size_t tile = (size_t)(m >> 8) * NKB + kb;
  unsigned short* dst = Aimg + tile * TSA + row * 32 + ((s4 ^ (row & 3)) << 3);
  *reinterpret_cast<uint4*>(dst) = o;
}

// ---------- W2 (= attn_w[:, H:2H]) -> bf16 image tiles [128 rows][32 k]
__global__ void __launch_bounds__(256) prep_b_kernel(
    const float* __restrict__ attn_w, unsigned short* __restrict__ Bimg) {
  const int idx = blockIdx.x * 256 + threadIdx.x;   // [0, 1024*128)
  const int n = idx >> 7, sl = idx & 127;
  const int kb = sl >> 2, s4 = sl & 3;
  const float4* src = reinterpret_cast<const float4*>(
      attn_w + (size_t)n * 2048 + 1024 + kb * BK + s4 * 8);
  float4 f0 = src[0], f1 = src[1];
  uint4 o;
  o.x = pack2(f0.x, f0.y); o.y = pack2(f0.z, f0.w);
  o.z = pack2(f1.x, f1.y); o.w = pack2(f1.z, f1.w);
  const int row = n & 127;
  const size_t tile = (size_t)(n >> 7) * NKB + kb;
  unsigned short* dst = Bimg + tile * TSB + row * 32 + ((s4 ^ (row & 3)) << 3);
  *reinterpret_cast<uint4*>(dst) = o;
}

#define LGKM0  asm volatile("s_waitcnt lgkmcnt(0)" ::: "memory")
#define VM0    asm volatile("s_waitcnt vmcnt(0)" ::: "memory")
#define VMCNT6 asm volatile("s_waitcnt vmcnt(6)" ::: "memory")
#define BARRIER __builtin_amdgcn_s_barrier()

// ---------- main GEMM: 256x128 tile, 4 waves (2Mx2N), 128x64 per wave, BK=32.
__global__ void __launch_bounds__(256, 1) gemm_img_kernel(
    const unsigned short* __restrict__ Aimg, const unsigned short* __restrict__ Bimg,
    const float* __restrict__ u, const float* __restrict__ v,
    float* __restrict__ pscore) {
  __shared__ unsigned short As[2][TSA];   // 32 KB
  __shared__ unsigned short Bs[2][TSB];   // 16 KB
  __shared__ float rowsum[2][256];        // 2 KB  -> 50 KB total, 2 blocks/CU

  const int tid = threadIdx.x;
  const int wid = tid >> 6, lane = tid & 63;
  const int wr = wid >> 1, wc = wid & 1;   // 2M x 2N waves

  const int wg = blockIdx.x;
  const int xcd = wg & 7, li = wg >> 3;           // 2048 blocks -> 256 per XCD
  const int rp = xcd * 32 + (li >> 3);            // A row panel 0..255 (256 rows)
  const int cb = li & 7;                          // col block 0..7 (128 cols)
  const int brow = rp * 256, bcol = cb * 128;

  const unsigned short* Ag = Aimg + (size_t)rp * NKB * TSA;
  const unsigned short* Bg = Bimg + (size_t)cb * NKB * TSB;

  f32x4 acc[8][4];
#pragma unroll
  for (int i = 0; i < 8; ++i)
#pragma unroll
    for (int j = 0; j < 4; ++j) acc[i][j] = (f32x4){0.f, 0.f, 0.f, 0.f};

  const int fr = lane & 15, g = lane >> 4;
  const int soff = ((g ^ (fr & 3)) << 3);         // shorts
  const int arow_base = (wr * 128 + fr) * 32;     // + m*512
  const int brow_base = (wc * 64 + fr) * 32;      // + n*512
  const int stg = tid * 8;                        // shorts

// issue 6 global_load_lds (4 A + 2 B, 16B each) for K-tile KB into buffer BUF
#define STAGE(BUF, KB)                                                          \
  do {                                                                          \
    const unsigned short* at_ = Ag + (KB) * TSA + stg;                          \
    const unsigned short* bt_ = Bg + (KB) * TSB + stg;                          \
    _Pragma("unroll")                                                           \
    for (int j_ = 0; j_ < 4; ++j_)                                              \
      __builtin_amdgcn_global_load_lds(                                         \
          (const __attribute__((address_space(1))) void*)(at_ + j_ * 2048),     \
          (__attribute__((address_space(3))) void*)(&As[BUF][stg + j_ * 2048]), \
          16, 0, 0);                                                            \
    _Pragma("unroll")                                                           \
    for (int j_ = 0; j_ < 2; ++j_)                                              \
      __builtin_amdgcn_global_load_lds(                                         \
          (const __attribute__((address_space(1))) void*)(bt_ + j_ * 2048),     \
          (__attribute__((address_space(3))) void*)(&Bs[BUF][stg + j_ * 2048]), \
          16, 0, 0);                                                            \
  } while (0)

// 12 ds_read_b128 + 32 MFMA on buffer BUF
#define COMPUTE(BUF)                                                            \
  do {                                                                          \
    short8 a_[8];                                                               \
    _Pragma("unroll")                                                           \
    for (int m_ = 0; m_ < 8; ++m_)                                              \
      a_[m_] = *reinterpret_cast<const short8*>(                                \
          &As[BUF][arow_base + m_ * 512 + soff]);                               \
    _Pragma("unroll")                                                           \
    for (int n_ = 0; n_ < 4; ++n_) {                                            \
      short8 b_ = *reinterpret_cast<const short8*>(                             \
          &Bs[BUF][brow_base + n_ * 512 + soff]);                               \
      _Pragma("unroll")                                                         \
      for (int m_ = 0; m_ < 8; ++m_)                                            \
        acc[m_][n_] = __builtin_amdgcn_mfma_f32_16x16x32_bf16(                  \
            a_[m_], b_, acc[m_][n_], 0, 0, 0);                                  \
    }                                                                           \
  } while (0)

  // prologue: stage K-tiles 0,1 (12 loads in flight per thread)
  STAGE(0, 0);
  STAGE(1, 1);
  int cur = 0;
#pragma unroll 1
  for (int t = 0; t < NKB; ++t) {
    if (t < NKB - 1) { VMCNT6; } else { VM0; }  // my 6 loads of tile t landed
    BARRIER;                                 // all waves' loads of tile t landed
    if (cur == 0) COMPUTE(0); else COMPUTE(1);
    LGKM0;                                   // my ds_reads of buf[cur] done
    BARRIER;                                 // all waves done reading buf[cur]
    if (t + 2 < NKB) {
      if (cur == 0) STAGE(0, t + 2); else STAGE(1, t + 2);
    }
    cur ^= 1;
  }
#undef STAGE
#undef COMPUTE

  // Epilogue: partial scores = sum_h v[h] * tanh(y + u[b,h]) over 128 cols
  float vv[4];
#pragma unroll
  for (int j = 0; j < 4; ++j) vv[j] = v[bcol + wc * 64 + j * 16 + fr];

  const int g4 = g * 4;
#pragma unroll
  for (int i = 0; i < 8; ++i) {
#pragma unroll
    for (int reg = 0; reg < 4; ++reg) {
      const int rloc = wr * 128 + i * 16 + g4 + reg;  // C/D row = (lane>>4)*4+reg
      const int bb = (brow + rloc) & (B_SZ - 1);      // m = s*B + b -> b = m & 31
      float rs = 0.f;
#pragma unroll
      for (int j = 0; j < 4; ++j) {
        const int h = bcol + wc * 64 + j * 16 + fr;   // C/D col = lane&15
        float val = acc[i][j][reg] + u[(size_t)bb * H_SZ + h];
        rs += vv[j] * fast_tanh(val);
      }
      rs += __shfl_xor(rs, 1);
      rs += __shfl_xor(rs, 2);
      rs += __shfl_xor(rs, 4);
      rs += __shfl_xor(rs, 8);
      if (fr == 0) rowsum[wc][rloc] = rs;
    }
  }
  __syncthreads();
  pscore[(size_t)cb * M_TOT + brow + tid] = rowsum[0][tid] + rowsum[1][tid];
}

// ================= fallback path (round-1, validated) for small ws =================
__global__ void __launch_bounds__(256) prep_w2_flat_kernel(
    const float* __restrict__ attn_w, unsigned short* __restrict__ Bt) {
  const int idx = blockIdx.x * 256 + threadIdx.x;
  const int base = idx * 4;
  const int n = base >> 10, k = base & 1023;
  float4 w = *reinterpret_cast<const float4*>(attn_w + (size_t)n * 2048 + 1024 + k);
  ushort4 o;
  o.x = f2bf(w.x); o.y = f2bf(w.y); o.z = f2bf(w.z); o.w = f2bf(w.w);
  *reinterpret_cast<ushort4*>(Bt + base) = o;
}

__global__ void __launch_bounds__(256) gemm_fused_kernel(
    const float* __restrict__ A, const unsigned short* __restrict__ Bt,
    const float* __restrict__ u, const float* __restrict__ v,
    float* __restrict__ pscore) {
  __shared__ unsigned short As[128 * 32];
  __shared__ unsigned short Bs[128 * 32];
  __shared__ float rowsum[2][128];
  const int tid = threadIdx.x;
  const int wid = tid >> 6, lane = tid & 63;
  const int wr = wid >> 1, wc = wid & 1;
  const int cb = blockIdx.x;
  const int brow = blockIdx.y * 128;
  const int bcol = cb * 128;
  const int arow_st = tid >> 1;
  const int acol_st = (tid & 1) * 16;
  const float* Ag = A + (size_t)(brow + arow_st) * K_TOT + acol_st;
  unsigned short* AsW = As + arow_st * 32 + acol_st;
  const int chunk0 = wid * 2;
  const unsigned short* Bg0 =
      Bt + (size_t)(bcol + chunk0 * 16 + (lane >> 2)) * K_TOT + (lane & 3) * 8;
  f32x4 acc[4][4];
#pragma unroll
  for (int i = 0; i < 4; ++i)
#pragma unroll
    for (int j = 0; j < 4; ++j) acc[i][j] = (f32x4){0.f, 0.f, 0.f, 0.f};
  const int fr = lane & 15;
  const int kseg = (lane >> 4) * 8;
  for (int k0 = 0; k0 < K_TOT; k0 += 32) {
    __syncthreads();
    const float4* ap = reinterpret_cast<const float4*>(Ag + k0);
    float4 f0 = ap[0], f1 = ap[1], f2 = ap[2], f3 = ap[3];
    uint4 w0, w1;
    w0.x = pack2(f0.x, f0.y); w0.y = pack2(f0.z, f0.w);
    w0.z = pack2(f1.x, f1.y); w0.w = pack2(f1.z, f1.w);
    w1.x = pack2(f2.x, f2.y); w1.y = pack2(f2.z, f2.w);
    w1.z = pack2(f3.x, f3.y); w1.w = pack2(f3.z, f3.w);
    *reinterpret_cast<uint4*>(AsW) = w0;
    *reinterpret_cast<uint4*>(AsW + 8) = w1;
    __builtin_amdgcn_global_load_lds(
        (const __attribute__((address_space(1))) void*)(Bg0 + k0),
        (__attribute__((address_space(3))) void*)(Bs + chunk0 * 512), 16, 0, 0);
    __builtin_amdgcn_global_load_lds(
        (const __attribute__((address_space(1))) void*)(Bg0 + 16 * K_TOT + k0),
        (__attribute__((address_space(3))) void*)(Bs + chunk0 * 512 + 512), 16, 0, 0);
    __syncthreads();
    short8 af[4], bf[4];
#pragma unroll
    for (int i = 0; i < 4; ++i)
      af[i] = *reinterpret_cast<const short8*>(As + (wr * 64 + i * 16 + fr) * 32 + kseg);
#pragma unroll
    for (int j = 0; j < 4; ++j)
      bf[j] = *reinterpret_cast<const short8*>(Bs + (wc * 64 + j * 16 + fr) * 32 + kseg);
#pragma unroll
    for (int i = 0; i < 4; ++i)
#pragma unroll
      for (int j = 0; j < 4; ++j)
        acc[i][j] = __builtin_amdgcn_mfma_f32_16x16x32_bf16(af[i], bf[j], acc[i][j], 0, 0, 0);
  }
  float vv[4];
#pragma unroll
  for (int j = 0; j < 4; ++j) vv[j] = v[bcol + wc * 64 + j * 16 + fr];
  const int g4 = (lane >> 4) * 4;
#pragma unroll
  for (int i = 0; i < 4; ++i) {
#pragma unroll
    for (int reg = 0; reg < 4; ++reg) {
      const int rloc = wr * 64 + i * 16 + g4 + reg;
      const int bb = (brow + rloc) & (B_SZ - 1);
      float rs = 0.f;
#pragma unroll
      for (int j = 0; j < 4; ++j) {
        const int h = bcol + wc * 64 + j * 16 + fr;
        float val = acc[i][j][reg] + u[(size_t)bb * H_SZ + h];
        rs += vv[j] * fast_tanh(val);
      }
      rs += __shfl_xor(rs, 1);
      rs += __shfl_xor(rs, 2);
      rs += __shfl_xor(rs, 4);
      rs += __shfl_xor(rs, 8);
      if (fr == 0) rowsum[wc][rloc] = rs;
    }
  }
  __syncthreads();
  if (tid < 128)
    pscore[(size_t)cb * M_TOT + brow + tid] = rowsum[0][tid] + rowsum[1][tid];
}
// ================= end fallback =================

// ncb = number of partial planes (8 both paths)
__global__ void __launch_bounds__(256) softmax_kernel(
    const float* __restrict__ ps, float* __restrict__ out, int ncb) {
  const int b = blockIdx.x, tid = threadIdx.x;
  const int wid = tid >> 6, lane = tid & 63;
  __shared__ float sred[4];
  float vals[8];
  float mx = -1e30f;
#pragma unroll
  for (int ii = 0; ii < 8; ++ii) {
    const int s = ii * 256 + tid;
    float sum = 0.f;
    for (int cbk = 0; cbk < ncb; ++cbk) sum += ps[(size_t)cbk * M_TOT + s * B_SZ + b];
    vals[ii] = sum;
    mx = fmaxf(mx, sum);
  }
#pragma unroll
  for (int m = 1; m < 64; m <<= 1) mx = fmaxf(mx, __shfl_xor(mx, m));
  if (lane == 0) sred[wid] = mx;
  __syncthreads();
  mx = fmaxf(fmaxf(sred[0], sred[1]), fmaxf(sred[2], sred[3]));
  __syncthreads();
  float es = 0.f;
#pragma unroll
  for (int ii = 0; ii < 8; ++ii) {
    vals[ii] = __expf(vals[ii] - mx);
    es += vals[ii];
  }
#pragma unroll
  for (int m = 1; m < 64; m <<= 1) es += __shfl_xor(es, m);
  if (lane == 0) sred[wid] = es;
  __syncthreads();
  es = sred[0] + sred[1] + sred[2] + sred[3];
  const float inv = 1.0f / es;
#pragma unroll
  for (int ii = 0; ii < 8; ++ii) out[(size_t)b * S_LEN + ii * 256 + tid] = vals[ii] * inv;
}

extern "C" void kernel_launch(void* const* d_in, const int* in_sizes, int n_in,
                              void* d_out, int out_size, void* d_ws, size_t ws_size,
                              hipStream_t stream) {
  const float* hidden = (const float*)d_in[0];   // [2,32,1024]
  const float* enc    = (const float*)d_in[1];   // [2048,32,1024] == A [65536][1024]
  const float* attn_w = (const float*)d_in[2];   // [1024][2048]
  const float* attn_b = (const float*)d_in[3];   // [1024]
  const float* v      = (const float*)d_in[4];   // [1024]
  float* out = (float*)d_out;                    // [32][2048]

  const size_t A_BYTES = (size_t)M_TOT * K_TOT * 2;      // 128 MB
  const size_t B_BYTES = (size_t)K_TOT * K_TOT * 2;      // 2 MB
  const size_t U_BYTES = (size_t)B_SZ * H_SZ * 4;        // 128 KB
  const size_t P_BYTES = (size_t)8 * M_TOT * 4;          // 2 MB
  char* w = (char*)d_ws;

  if (ws_size >= A_BYTES + B_BYTES + U_BYTES + P_BYTES) {
    unsigned short* Aimg = (unsigned short*)w;
    unsigned short* Bimg = (unsigned short*)(w + A_BYTES);
    float* u  = (float*)(w + A_BYTES + B_BYTES);
    float* ps = (float*)(w + A_BYTES + B_BYTES + U_BYTES);
    prep_u_kernel<<<dim3(4, 8), 256, 0, stream>>>(hidden, attn_w, attn_b, u);
    prep_b_kernel<<<512, 256, 0, stream>>>(attn_w, Bimg);
    prep_a_kernel<<<M_TOT * 128 / 256, 256, 0, stream>>>(enc, Aimg);
    gemm_img_kernel<<<NCB * (M_TOT / 256), 256, 0, stream>>>(Aimg, Bimg, u, v, ps);
    softmax_kernel<<<B_SZ, 256, 0, stream>>>(ps, out, NCB);
  } else {
    // fallback: round-1 validated path (~4.2 MB ws)
    unsigned short* Bt = (unsigned short*)w;
    float* u  = (float*)(w + B_BYTES);
    float* ps = (float*)(w + B_BYTES + U_BYTES);
    prep_u_kernel<<<dim3(4, 8), 256, 0, stream>>>(hidden, attn_w, attn_b, u);
    prep_w2_flat_kernel<<<1024, 256, 0, stream>>>(attn_w, Bt);
    gemm_fused_kernel<<<dim3(8, M_TOT / 128), 256, 0, stream>>>(enc, Bt, u, v, ps);
    softmax_kernel<<<B_SZ, 256, 0, stream>>>(ps, out, 8);
  }
}

// Round 16
// 363.877 us; speedup vs baseline: 1.4306x; 1.4306x over previous
//
#include <hip/hip_runtime.h>
#include <stdint.h>

// scores[b,s] = v . tanh( W1@hidden[-1,b] + W2@enc[s,b] + bias ); out = softmax_s
// GEMM: [M=65536,K=1024] x [N=1024,K=1024]^T in bf16 MFMA.
// r16 = consolidation: r5's hardware-validated GEMM (single-buffered 128x128
// tile, 4 waves, acc[4][4] ~96 VGPR -> 2.6 blocks/CU, 245us measured, 0 bank
// conflicts) + improved prep_u (validated r8-r15). Exploration r8-r15 showed
// every bigger-tile / deeper-pipeline variant loses to this structure on this
// toolchain (register-residency cliff at >~200 regs; 512-thread kernels cap
// at 128 VGPR).

#define S_LEN 2048
#define B_SZ 32
#define H_SZ 1024
#define M_TOT (S_LEN * B_SZ)   // 65536
#define K_TOT H_SZ             // 1024
#define NCB 8                  // col-blocks = N / 128
#define BK 64
#define TILE_SHORTS 8192       // 128 rows * 64 k * bf16 = 16 KB

typedef __attribute__((ext_vector_type(8))) short short8;
typedef __attribute__((ext_vector_type(4))) float f32x4;

static __device__ __forceinline__ unsigned short f2bf(float x) {
  uint32_t u = __builtin_bit_cast(uint32_t, x);
  u += 0x7FFFu + ((u >> 16) & 1u);
  return (unsigned short)(u >> 16);
}
static __device__ __forceinline__ uint32_t pack2(float a, float b) {
  return (uint32_t)f2bf(a) | ((uint32_t)f2bf(b) << 16);
}
static __device__ __forceinline__ float fast_tanh(float x) {
  float e = __expf(2.0f * x);
  return 1.0f - 2.0f / (e + 1.0f);
}

// ---------- u[b][h] = dot(attn_w[h, 0:H], hidden[-1,b,:]) + attn_b[h]
// 4 b's per block: W1 read 8x (32 MB) instead of 32x (128 MB).
__global__ void __launch_bounds__(256) prep_u_kernel(
    const float* __restrict__ hidden, const float* __restrict__ attn_w,
    const float* __restrict__ attn_b, float* __restrict__ u) {
  __shared__ float hs[4][H_SZ];
  const int hc = blockIdx.x;   // 0..3  (h chunk)
  const int bg = blockIdx.y;   // 0..7  (batch group of 4)
  const int tid = threadIdx.x;
  for (int i = tid; i < 4 * H_SZ; i += 256) {
    const int bi = i >> 10, k = i & 1023;
    hs[bi][k] = hidden[(size_t)B_SZ * H_SZ + (size_t)(bg * 4 + bi) * H_SZ + k];
  }
  __syncthreads();
  const int h = hc * 256 + tid;
  const float* wrow = attn_w + (size_t)h * (2 * H_SZ);
  float s0 = 0.f, s1 = 0.f, s2 = 0.f, s3 = 0.f;
#pragma unroll 4
  for (int k = 0; k < H_SZ; k += 4) {
    float4 w4 = *reinterpret_cast<const float4*>(wrow + k);
    s0 += w4.x * hs[0][k] + w4.y * hs[0][k + 1] + w4.z * hs[0][k + 2] + w4.w * hs[0][k + 3];
    s1 += w4.x * hs[1][k] + w4.y * hs[1][k + 1] + w4.z * hs[1][k + 2] + w4.w * hs[1][k + 3];
    s2 += w4.x * hs[2][k] + w4.y * hs[2][k + 1] + w4.z * hs[2][k + 2] + w4.w * hs[2][k + 3];
    s3 += w4.x * hs[3][k] + w4.y * hs[3][k + 1] + w4.z * hs[3][k + 2] + w4.w * hs[3][k + 3];
  }
  const float bb = attn_b[h];
  u[(size_t)(bg * 4 + 0) * H_SZ + h] = s0 + bb;
  u[(size_t)(bg * 4 + 1) * H_SZ + h] = s1 + bb;
  u[(size_t)(bg * 4 + 2) * H_SZ + h] = s2 + bb;
  u[(size_t)(bg * 4 + 3) * H_SZ + h] = s3 + bb;
}

// ---------- enc f32 -> bf16 LDS-image tiles.
// tile (rp, kb) at (rp*16+kb)*8192 shorts; within tile:
// row r (0..127) * 64 shorts, 16B slot s8 stored at (s8 ^ (r&7)).
__global__ void __launch_bounds__(256) prep_a_kernel(
    const float* __restrict__ enc, unsigned short* __restrict__ Aimg) {
  const int idx = blockIdx.x * 256 + threadIdx.x;   // [0, M_TOT*128)
  const int m = idx >> 7, sl = idx & 127;
  const int kb = sl >> 3, s8 = sl & 7;
  const float4* src =
      reinterpret_cast<const float4*>(enc + (size_t)m * K_TOT + kb * BK + s8 * 8);
  float4 f0 = src[0], f1 = src[1];
  uint4 o;
  o.x = pack2(f0.x, f0.y); o.y = pack2(f0.z, f0.w);
  o.z = pack2(f1.x, f1.y); o.w = pack2(f1.z, f1.w);
  const int row = m & 127;
  const size_t tile = (size_t)(m >> 7) * 16 + kb;
  unsigned short* dst = Aimg + tile * TILE_SHORTS + row * 64 + ((s8 ^ (row & 7)) << 3);
  *reinterpret_cast<uint4*>(dst) = o;
}

// ---------- W2 (= attn_w[:, H:2H]) -> bf16 LDS-image tiles, same layout
__global__ void __launch_bounds__(256) prep_b_kernel(
    const float* __restrict__ attn_w, unsigned short* __restrict__ Bimg) {
  const int idx = blockIdx.x * 256 + threadIdx.x;   // [0, 1024*128)
  const int n = idx >> 7, sl = idx & 127;
  const int kb = sl >> 3, s8 = sl & 7;
  const float4* src = reinterpret_cast<const float4*>(
      attn_w + (size_t)n * 2048 + 1024 + kb * BK + s8 * 8);
  float4 f0 = src[0], f1 = src[1];
  uint4 o;
  o.x = pack2(f0.x, f0.y); o.y = pack2(f0.z, f0.w);
  o.z = pack2(f1.x, f1.y); o.w = pack2(f1.z, f1.w);
  const int row = n & 127;
  const size_t tile = (size_t)(n >> 7) * 16 + kb;
  unsigned short* dst = Bimg + tile * TILE_SHORTS + row * 64 + ((s8 ^ (row & 7)) << 3);
  *reinterpret_cast<uint4*>(dst) = o;
}

// ---------- main GEMM (r5-validated: pure bf16, both operands via
// global_load_lds, single-buffered, 2 syncthreads/K-tile, 33KB LDS ->
// ~2.6 blocks/CU; cross-block TLP hides the drain).
// grid: 4096 blocks 1-D, XCD-swizzled: xcd = wg&7 owns row panels [xcd*64,+64).
__global__ void __launch_bounds__(256) gemm_img_kernel(
    const unsigned short* __restrict__ Aimg, const unsigned short* __restrict__ Bimg,
    const float* __restrict__ u, const float* __restrict__ v,
    float* __restrict__ pscore) {
  __shared__ unsigned short As[TILE_SHORTS];
  __shared__ unsigned short Bs[TILE_SHORTS];
  __shared__ float rowsum[2][128];

  const int tid = threadIdx.x;
  const int wid = tid >> 6, lane = tid & 63;
  const int wr = wid >> 1, wc = wid & 1;

  const int wg = blockIdx.x;
  const int xcd = wg & 7, li = wg >> 3;
  const int rp = xcd * 64 + (li >> 3);
  const int cb = li & 7;
  const int brow = rp * 128, bcol = cb * 128;

  const unsigned short* Ag = Aimg + (size_t)rp * 16 * TILE_SHORTS;
  const unsigned short* Bg = Bimg + (size_t)cb * 16 * TILE_SHORTS;

  f32x4 acc[4][4];
#pragma unroll
  for (int i = 0; i < 4; ++i)
#pragma unroll
    for (int j = 0; j < 4; ++j) acc[i][j] = (f32x4){0.f, 0.f, 0.f, 0.f};

  const int fr = lane & 15, g = lane >> 4;
  // swizzled 16B-slot offsets (shorts) for the two K=32 halves of a BK=64 row
  const int soff0 = ((g) ^ (fr & 7)) << 3;
  const int soff1 = ((4 + g) ^ (fr & 7)) << 3;
  const int arow_base = (wr * 64 + fr) * 64;
  const int brow_base = (wc * 64 + fr) * 64;
  // staging: wave wid covers quarter wid of each tile; 4 loads x 1KB each
  const int stg = wid * 2048;  // shorts

  for (int kb = 0; kb < 16; ++kb) {
    __syncthreads();  // previous iteration's LDS reads complete
    const unsigned short* at = Ag + kb * TILE_SHORTS + stg + lane * 8;
    const unsigned short* bt = Bg + kb * TILE_SHORTS + stg + lane * 8;
#pragma unroll
    for (int j = 0; j < 4; ++j) {
      __builtin_amdgcn_global_load_lds(
          (const __attribute__((address_space(1))) void*)(at + j * 512),
          (__attribute__((address_space(3))) void*)(As + stg + j * 512), 16, 0, 0);
      __builtin_amdgcn_global_load_lds(
          (const __attribute__((address_space(1))) void*)(bt + j * 512),
          (__attribute__((address_space(3))) void*)(Bs + stg + j * 512), 16, 0, 0);
    }
    __syncthreads();  // staging complete (compiler drains vmcnt/lgkmcnt)

    short8 af[4], bf[4];
#pragma unroll
    for (int i = 0; i < 4; ++i)
      af[i] = *reinterpret_cast<const short8*>(As + arow_base + i * 1024 + soff0);
#pragma unroll
    for (int j = 0; j < 4; ++j)
      bf[j] = *reinterpret_cast<const short8*>(Bs + brow_base + j * 1024 + soff0);
#pragma unroll
    for (int i = 0; i < 4; ++i)
#pragma unroll
      for (int j = 0; j < 4; ++j)
        acc[i][j] = __builtin_amdgcn_mfma_f32_16x16x32_bf16(af[i], bf[j], acc[i][j], 0, 0, 0);
#pragma unroll
    for (int i = 0; i < 4; ++i)
      af[i] = *reinterpret_cast<const short8*>(As + arow_base + i * 1024 + soff1);
#pragma unroll
    for (int j = 0; j < 4; ++j)
      bf[j] = *reinterpret_cast<const short8*>(Bs + brow_base + j * 1024 + soff1);
#pragma unroll
    for (int i = 0; i < 4; ++i)
#pragma unroll
      for (int j = 0; j < 4; ++j)
        acc[i][j] = __builtin_amdgcn_mfma_f32_16x16x32_bf16(af[i], bf[j], acc[i][j], 0, 0, 0);
  }

  // Epilogue: partial scores = sum_h v[h] * tanh(y + u[b,h]) over this tile's cols
  float vv[4];
#pragma unroll
  for (int j = 0; j < 4; ++j) vv[j] = v[bcol + wc * 64 + j * 16 + fr];

  const int g4 = g * 4;
#pragma unroll
  for (int i = 0; i < 4; ++i) {
#pragma unroll
    for (int reg = 0; reg < 4; ++reg) {
      const int rloc = wr * 64 + i * 16 + g4 + reg;  // C/D row = (lane>>4)*4+reg
      const int bb = (brow + rloc) & (B_SZ - 1);     // m = s*B + b -> b = m & 31
      float rs = 0.f;
#pragma unroll
      for (int j = 0; j < 4; ++j) {
        const int h = bcol + wc * 64 + j * 16 + fr;  // C/D col = lane&15
        float val = acc[i][j][reg] + u[(size_t)bb * H_SZ + h];
        rs += vv[j] * fast_tanh(val);
      }
      rs += __shfl_xor(rs, 1);
      rs += __shfl_xor(rs, 2);
      rs += __shfl_xor(rs, 4);
      rs += __shfl_xor(rs, 8);
      if (fr == 0) rowsum[wc][rloc] = rs;
    }
  }
  __syncthreads();
  if (tid < 128)
    pscore[(size_t)cb * M_TOT + brow + tid] = rowsum[0][tid] + rowsum[1][tid];
}

// ================= fallback path (round-1, validated) for small ws =================
__global__ void __launch_bounds__(256) prep_w2_flat_kernel(
    const float* __restrict__ attn_w, unsigned short* __restrict__ Bt) {
  const int idx = blockIdx.x * 256 + threadIdx.x;
  const int base = idx * 4;
  const int n = base >> 10, k = base & 1023;
  float4 w = *reinterpret_cast<const float4*>(attn_w + (size_t)n * 2048 + 1024 + k);
  ushort4 o;
  o.x = f2bf(w.x); o.y = f2bf(w.y); o.z = f2bf(w.z); o.w = f2bf(w.w);
  *reinterpret_cast<ushort4*>(Bt + base) = o;
}

__global__ void __launch_bounds__(256) gemm_fused_kernel(
    const float* __restrict__ A, const unsigned short* __restrict__ Bt,
    const float* __restrict__ u, const float* __restrict__ v,
    float* __restrict__ pscore) {
  __shared__ unsigned short As[128 * 32];
  __shared__ unsigned short Bs[128 * 32];
  __shared__ float rowsum[2][128];
  const int tid = threadIdx.x;
  const int wid = tid >> 6, lane = tid & 63;
  const int wr = wid >> 1, wc = wid & 1;
  const int cb = blockIdx.x;
  const int brow = blockIdx.y * 128;
  const int bcol = cb * 128;
  const int arow_st = tid >> 1;
  const int acol_st = (tid & 1) * 16;
  const float* Ag = A + (size_t)(brow + arow_st) * K_TOT + acol_st;
  unsigned short* AsW = As + arow_st * 32 + acol_st;
  const int chunk0 = wid * 2;
  const unsigned short* Bg0 =
      Bt + (size_t)(bcol + chunk0 * 16 + (lane >> 2)) * K_TOT + (lane & 3) * 8;
  f32x4 acc[4][4];
#pragma unroll
  for (int i = 0; i < 4; ++i)
#pragma unroll
    for (int j = 0; j < 4; ++j) acc[i][j] = (f32x4){0.f, 0.f, 0.f, 0.f};
  const int fr = lane & 15;
  const int kseg = (lane >> 4) * 8;
  for (int k0 = 0; k0 < K_TOT; k0 += 32) {
    __syncthreads();
    const float4* ap = reinterpret_cast<const float4*>(Ag + k0);
    float4 f0 = ap[0], f1 = ap[1], f2 = ap[2], f3 = ap[3];
    uint4 w0, w1;
    w0.x = pack2(f0.x, f0.y); w0.y = pack2(f0.z, f0.w);
    w0.z = pack2(f1.x, f1.y); w0.w = pack2(f1.z, f1.w);
    w1.x = pack2(f2.x, f2.y); w1.y = pack2(f2.z, f2.w);
    w1.z = pack2(f3.x, f3.y); w1.w = pack2(f3.z, f3.w);
    *reinterpret_cast<uint4*>(AsW) = w0;
    *reinterpret_cast<uint4*>(AsW + 8) = w1;
    __builtin_amdgcn_global_load_lds(
        (const __attribute__((address_space(1))) void*)(Bg0 + k0),
        (__attribute__((address_space(3))) void*)(Bs + chunk0 * 512), 16, 0, 0);
    __builtin_amdgcn_global_load_lds(
        (const __attribute__((address_space(1))) void*)(Bg0 + 16 * K_TOT + k0),
        (__attribute__((address_space(3))) void*)(Bs + chunk0 * 512 + 512), 16, 0, 0);
    __syncthreads();
    short8 af[4], bf[4];
#pragma unroll
    for (int i = 0; i < 4; ++i)
      af[i] = *reinterpret_cast<const short8*>(As + (wr * 64 + i * 16 + fr) * 32 + kseg);
#pragma unroll
    for (int j = 0; j < 4; ++j)
      bf[j] = *reinterpret_cast<const short8*>(Bs + (wc * 64 + j * 16 + fr) * 32 + kseg);
#pragma unroll
    for (int i = 0; i < 4; ++i)
#pragma unroll
      for (int j = 0; j < 4; ++j)
        acc[i][j] = __builtin_amdgcn_mfma_f32_16x16x32_bf16(af[i], bf[j], acc[i][j], 0, 0, 0);
  }
  float vv[4];
#pragma unroll
  for (int j = 0; j < 4; ++j) vv[j] = v[bcol + wc * 64 + j * 16 + fr];
  const int g4 = (lane >> 4) * 4;
#pragma unroll
  for (int i = 0; i < 4; ++i) {
#pragma unroll
    for (int reg = 0; reg < 4; ++reg) {
      const int rloc = wr * 64 + i * 16 + g4 + reg;
      const int bb = (brow + rloc) & (B_SZ - 1);
      float rs = 0.f;
#pragma unroll
      for (int j = 0; j < 4; ++j) {
        const int h = bcol + wc * 64 + j * 16 + fr;
        float val = acc[i][j][reg] + u[(size_t)bb * H_SZ + h];
        rs += vv[j] * fast_tanh(val);
      }
      rs += __shfl_xor(rs, 1);
      rs += __shfl_xor(rs, 2);
      rs += __shfl_xor(rs, 4);
      rs += __shfl_xor(rs, 8);
      if (fr == 0) rowsum[wc][rloc] = rs;
    }
  }
  __syncthreads();
  if (tid < 128)
    pscore[(size_t)cb * M_TOT + brow + tid] = rowsum[0][tid] + rowsum[1][tid];
}
// ================= end fallback =================

__global__ void __launch_bounds__(256) softmax_kernel(
    const float* __restrict__ ps, float* __restrict__ out) {
  const int b = blockIdx.x, tid = threadIdx.x;
  const int wid = tid >> 6, lane = tid & 63;
  __shared__ float sred[4];
  float vals[8];
  float mx = -1e30f;
#pragma unroll
  for (int ii = 0; ii < 8; ++ii) {
    const int s = ii * 256 + tid;
    float sum = 0.f;
#pragma unroll
    for (int cbk = 0; cbk < NCB; ++cbk) sum += ps[(size_t)cbk * M_TOT + s * B_SZ + b];
    vals[ii] = sum;
    mx = fmaxf(mx, sum);
  }
#pragma unroll
  for (int m = 1; m < 64; m <<= 1) mx = fmaxf(mx, __shfl_xor(mx, m));
  if (lane == 0) sred[wid] = mx;
  __syncthreads();
  mx = fmaxf(fmaxf(sred[0], sred[1]), fmaxf(sred[2], sred[3]));
  __syncthreads();
  float es = 0.f;
#pragma unroll
  for (int ii = 0; ii < 8; ++ii) {
    vals[ii] = __expf(vals[ii] - mx);
    es += vals[ii];
  }
#pragma unroll
  for (int m = 1; m < 64; m <<= 1) es += __shfl_xor(es, m);
  if (lane == 0) sred[wid] = es;
  __syncthreads();
  es = sred[0] + sred[1] + sred[2] + sred[3];
  const float inv = 1.0f / es;
#pragma unroll
  for (int ii = 0; ii < 8; ++ii) out[(size_t)b * S_LEN + ii * 256 + tid] = vals[ii] * inv;
}

extern "C" void kernel_launch(void* const* d_in, const int* in_sizes, int n_in,
                              void* d_out, int out_size, void* d_ws, size_t ws_size,
                              hipStream_t stream) {
  const float* hidden = (const float*)d_in[0];   // [2,32,1024]
  const float* enc    = (const float*)d_in[1];   // [2048,32,1024] == A [65536][1024]
  const float* attn_w = (const float*)d_in[2];   // [1024][2048]
  const float* attn_b = (const float*)d_in[3];   // [1024]
  const float* v      = (const float*)d_in[4];   // [1024]
  float* out = (float*)d_out;                    // [32][2048]

  const size_t A_BYTES = (size_t)M_TOT * K_TOT * 2;      // 128 MB
  const size_t B_BYTES = (size_t)K_TOT * K_TOT * 2;      // 2 MB
  const size_t U_BYTES = (size_t)B_SZ * H_SZ * 4;        // 128 KB
  const size_t P_BYTES = (size_t)NCB * M_TOT * 4;        // 2 MB
  char* w = (char*)d_ws;

  if (ws_size >= A_BYTES + B_BYTES + U_BYTES + P_BYTES) {
    unsigned short* Aimg = (unsigned short*)w;
    unsigned short* Bimg = (unsigned short*)(w + A_BYTES);
    float* u  = (float*)(w + A_BYTES + B_BYTES);
    float* ps = (float*)(w + A_BYTES + B_BYTES + U_BYTES);
    prep_u_kernel<<<dim3(4, 8), 256, 0, stream>>>(hidden, attn_w, attn_b, u);
    prep_b_kernel<<<512, 256, 0, stream>>>(attn_w, Bimg);
    prep_a_kernel<<<M_TOT * 128 / 256, 256, 0, stream>>>(enc, Aimg);
    gemm_img_kernel<<<NCB * (M_TOT / 128), 256, 0, stream>>>(Aimg, Bimg, u, v, ps);
    softmax_kernel<<<B_SZ, 256, 0, stream>>>(ps, out);
  } else {
    // fallback: round-1 validated path (~4.2 MB ws)
    unsigned short* Bt = (unsigned short*)w;
    float* u  = (float*)(w + B_BYTES);
    float* ps = (float*)(w + B_BYTES + U_BYTES);
    prep_u_kernel<<<dim3(4, 8), 256, 0, stream>>>(hidden, attn_w, attn_b, u);
    prep_w2_flat_kernel<<<1024, 256, 0, stream>>>(attn_w, Bt);
    gemm_fused_kernel<<<dim3(NCB, M_TOT / 128), 256, 0, stream>>>(enc, Bt, u, v, ps);
    softmax_kernel<<<B_SZ, 256, 0, stream>>>(ps, out);
  }
}